// Round 2
// baseline (178.912 us; speedup 1.0000x reference)
//
#include <hip/hip_runtime.h>

// SSIM loss, fused. Input: enhanced, target fp32 [16,3,512,512]. Output: scalar fp32.
// V3: interior/edge block specialization (branch-free loads for 70% of blocks),
// vertical pass as column-wise ds_read_b32 (2-way bank aliasing = free),
// products-once horizontal pass, rcp+NR division.

#define TILE_W 64
#define TILE_H 16
#define HALO 3
#define IN_H (TILE_H + 2 * HALO)      // 22
#define H_STRIDE 68                   // 64 + 4: 16B-aligned, rotates banks by 4/row
#define CH_STRIDE (IN_H * H_STRIDE)   // 1496 floats per channel
#define IMG_H 512
#define IMG_W 512
#define NPLANES 48                    // 16 * 3
#define SSIM_C1 1.0e-4f
#define SSIM_C2 9.0e-4f

__device__ __constant__ float c_g[7] = {
    0.03663284536f, 0.11128076166f, 0.21674531251f, 0.27068216094f,
    0.21674531251f, 0.11128076166f, 0.03663284536f};

// Aligned float4 load with zero fill outside [0, IMG_W). col is a multiple of 4.
__device__ __forceinline__ float4 ld4z(const float* __restrict__ row, int col) {
  if (col >= 0 && col + 3 < IMG_W) {
    return *reinterpret_cast<const float4*>(row + col);
  }
  float4 v;
  v.x = ((unsigned)(col + 0) < IMG_W) ? row[col + 0] : 0.f;
  v.y = ((unsigned)(col + 1) < IMG_W) ? row[col + 1] : 0.f;
  v.z = ((unsigned)(col + 2) < IMG_W) ? row[col + 2] : 0.f;
  v.w = ((unsigned)(col + 3) < IMG_W) ? row[col + 3] : 0.f;
  return v;
}

__global__ __launch_bounds__(256, 5) void ssim_tile_kernel(
    const float* __restrict__ x, const float* __restrict__ y,
    float* __restrict__ partial) {
  // 5 channels (mu1, mu2, xx, yy, xy) of horizontally-filtered rows.
  __shared__ __align__(16) float hbuf[5 * CH_STRIDE];  // 29,920 B -> 5 blocks/CU

  const int tid = threadIdx.x;
  const int plane = blockIdx.z;
  const float* __restrict__ xp = x + (size_t)plane * (IMG_H * IMG_W);
  const float* __restrict__ yp = y + (size_t)plane * (IMG_H * IMG_W);
  const int y0 = blockIdx.y * TILE_H - HALO;
  const int cbase = blockIdx.x * TILE_W - 4;  // window col 0 (output col - 4)
  // Block-uniform: does this block ever touch an image border?
  const bool edge = (blockIdx.x == 0) | (blockIdx.x == gridDim.x - 1) |
                    (blockIdx.y == 0) | (blockIdx.y == gridDim.y - 1);

  // ---- Horizontal 7-tap pass: each item = (row, 4 adjacent output cols). ----
  // 12-float window [cbase+4cg .. +11]; output j uses window indices j+1..j+7.
  for (int item = tid; item < IN_H * 16; item += 256) {
    const int hr = item >> 4;
    const int cg = item & 15;
    const int bcol = cbase + 4 * cg;
    float xin[12], yin[12];
    if (!edge) {
      // Interior: all addresses in-bounds by construction, zero checks.
      const float* xr = xp + (size_t)(y0 + hr) * IMG_W + bcol;
      const float* yr = yp + (size_t)(y0 + hr) * IMG_W + bcol;
      const float4 xa = *reinterpret_cast<const float4*>(xr);
      const float4 xb = *reinterpret_cast<const float4*>(xr + 4);
      const float4 xc = *reinterpret_cast<const float4*>(xr + 8);
      const float4 ya = *reinterpret_cast<const float4*>(yr);
      const float4 yb = *reinterpret_cast<const float4*>(yr + 4);
      const float4 yc = *reinterpret_cast<const float4*>(yr + 8);
      xin[0] = xa.x; xin[1] = xa.y; xin[2] = xa.z; xin[3] = xa.w;
      xin[4] = xb.x; xin[5] = xb.y; xin[6] = xb.z; xin[7] = xb.w;
      xin[8] = xc.x; xin[9] = xc.y; xin[10] = xc.z; xin[11] = xc.w;
      yin[0] = ya.x; yin[1] = ya.y; yin[2] = ya.z; yin[3] = ya.w;
      yin[4] = yb.x; yin[5] = yb.y; yin[6] = yb.z; yin[7] = yb.w;
      yin[8] = yc.x; yin[9] = yc.y; yin[10] = yc.z; yin[11] = yc.w;
    } else {
      const int gy = y0 + hr;
      if ((unsigned)gy < IMG_H) {
        const float* xr = xp + (size_t)gy * IMG_W;
        const float* yr = yp + (size_t)gy * IMG_W;
#pragma unroll
        for (int v = 0; v < 3; ++v) {
          const float4 a = ld4z(xr, bcol + 4 * v);
          const float4 b = ld4z(yr, bcol + 4 * v);
          xin[4 * v + 0] = a.x; xin[4 * v + 1] = a.y;
          xin[4 * v + 2] = a.z; xin[4 * v + 3] = a.w;
          yin[4 * v + 0] = b.x; yin[4 * v + 1] = b.y;
          yin[4 * v + 2] = b.z; yin[4 * v + 3] = b.w;
        }
      } else {
#pragma unroll
        for (int i = 0; i < 12; ++i) { xin[i] = 0.f; yin[i] = 0.f; }
      }
    }
    // Products once per window column, scatter into the <=4 outputs using it.
    float a1[4] = {0.f, 0.f, 0.f, 0.f};
    float a2[4] = {0.f, 0.f, 0.f, 0.f};
    float axx[4] = {0.f, 0.f, 0.f, 0.f};
    float ayy[4] = {0.f, 0.f, 0.f, 0.f};
    float axy[4] = {0.f, 0.f, 0.f, 0.f};
#pragma unroll
    for (int w = 1; w < 12; ++w) {
      const float xv = xin[w];
      const float yv = yin[w];
      const float pxx = xv * xv;
      const float pyy = yv * yv;
      const float pxy = xv * yv;
#pragma unroll
      for (int j = 0; j < 4; ++j) {
        const int k = w - 1 - j;  // tap index for output j
        if (k >= 0 && k < 7) {
          const float gk = c_g[k];
          a1[j] = fmaf(gk, xv, a1[j]);
          a2[j] = fmaf(gk, yv, a2[j]);
          axx[j] = fmaf(gk, pxx, axx[j]);
          ayy[j] = fmaf(gk, pyy, ayy[j]);
          axy[j] = fmaf(gk, pxy, axy[j]);
        }
      }
    }
    float* hb = &hbuf[hr * H_STRIDE + 4 * cg];
    *reinterpret_cast<float4*>(hb + 0 * CH_STRIDE) =
        make_float4(a1[0], a1[1], a1[2], a1[3]);
    *reinterpret_cast<float4*>(hb + 1 * CH_STRIDE) =
        make_float4(a2[0], a2[1], a2[2], a2[3]);
    *reinterpret_cast<float4*>(hb + 2 * CH_STRIDE) =
        make_float4(axx[0], axx[1], axx[2], axx[3]);
    *reinterpret_cast<float4*>(hb + 3 * CH_STRIDE) =
        make_float4(ayy[0], ayy[1], ayy[2], ayy[3]);
    *reinterpret_cast<float4*>(hb + 4 * CH_STRIDE) =
        make_float4(axy[0], axy[1], axy[2], axy[3]);
  }
  __syncthreads();

  // ---- Vertical 7-tap pass + SSIM map. ----
  // Thread = (column c, 4 consecutive output rows r0..r0+3). Lane index = c,
  // so every ds_read_b32 hits banks (c + const) % 32: 2-way aliasing = free.
  const int c = tid & 63;
  const int r0 = (tid >> 6) * 4;  // wave w owns rows 4w..4w+3
  const float* hb = &hbuf[r0 * H_STRIDE + c];
  float m1[4] = {0.f, 0.f, 0.f, 0.f};
  float m2[4] = {0.f, 0.f, 0.f, 0.f};
  float exx[4] = {0.f, 0.f, 0.f, 0.f};
  float eyy[4] = {0.f, 0.f, 0.f, 0.f};
  float exy[4] = {0.f, 0.f, 0.f, 0.f};
#pragma unroll
  for (int j = 0; j < 10; ++j) {  // input rows r0+j, all offsets immediate
    const float v1 = hb[0 * CH_STRIDE + j * H_STRIDE];
    const float v2 = hb[1 * CH_STRIDE + j * H_STRIDE];
    const float vxx = hb[2 * CH_STRIDE + j * H_STRIDE];
    const float vyy = hb[3 * CH_STRIDE + j * H_STRIDE];
    const float vxy = hb[4 * CH_STRIDE + j * H_STRIDE];
#pragma unroll
    for (int t = 0; t < 4; ++t) {
      const int k = j - t;  // tap index for output row r0+t
      if (k >= 0 && k < 7) {
        const float gk = c_g[k];
        m1[t] = fmaf(gk, v1, m1[t]);
        m2[t] = fmaf(gk, v2, m2[t]);
        exx[t] = fmaf(gk, vxx, exx[t]);
        eyy[t] = fmaf(gk, vyy, eyy[t]);
        exy[t] = fmaf(gk, vxy, exy[t]);
      }
    }
  }

  float acc = 0.f;
#pragma unroll
  for (int t = 0; t < 4; ++t) {
    const float mu1sq = m1[t] * m1[t];
    const float mu2sq = m2[t] * m2[t];
    const float mu12 = m1[t] * m2[t];
    const float s1 = exx[t] - mu1sq;
    const float s2 = eyy[t] - mu2sq;
    const float s12 = exy[t] - mu12;
    const float num = (2.f * mu12 + SSIM_C1) * (2.f * s12 + SSIM_C2);
    const float den = (mu1sq + mu2sq + SSIM_C1) * (s1 + s2 + SSIM_C2);
    // den > 0 always; rcp + 1 Newton step ~= 1 ulp.
    float r = __builtin_amdgcn_rcpf(den);
    r = r * fmaf(-den, r, 2.f);
    acc = fmaf(num, r, acc);
  }

  // Block reduction: wave64 shuffle tree, then LDS across 4 waves.
#pragma unroll
  for (int off = 32; off > 0; off >>= 1) acc += __shfl_down(acc, off, 64);
  __shared__ float wsum[4];
  if ((tid & 63) == 0) wsum[tid >> 6] = acc;
  __syncthreads();
  if (tid == 0) {
    const float s = wsum[0] + wsum[1] + wsum[2] + wsum[3];
    partial[(size_t)blockIdx.z * gridDim.x * gridDim.y +
            (size_t)blockIdx.y * gridDim.x + blockIdx.x] = s;
  }
}

__global__ __launch_bounds__(1024) void ssim_reduce_kernel(
    const float* __restrict__ partial, int n, float* __restrict__ out) {
  float acc = 0.f;
  const int nv = n >> 2;  // n = 12288, divisible by 4
  const float4* __restrict__ p4 = reinterpret_cast<const float4*>(partial);
  for (int i = threadIdx.x; i < nv; i += 1024) {
    const float4 v = p4[i];
    acc += (v.x + v.y) + (v.z + v.w);
  }
#pragma unroll
  for (int off = 32; off > 0; off >>= 1) acc += __shfl_down(acc, off, 64);
  __shared__ float wsum[16];
  if ((threadIdx.x & 63) == 0) wsum[threadIdx.x >> 6] = acc;
  __syncthreads();
  if (threadIdx.x == 0) {
    float s = 0.f;
#pragma unroll
    for (int w = 0; w < 16; ++w) s += wsum[w];
    out[0] = 1.f - s * (1.f / (float)(NPLANES * IMG_H * IMG_W));
  }
}

extern "C" void kernel_launch(void* const* d_in, const int* in_sizes, int n_in,
                              void* d_out, int out_size, void* d_ws, size_t ws_size,
                              hipStream_t stream) {
  const float* enhanced = (const float*)d_in[0];
  const float* target = (const float*)d_in[1];
  float* out = (float*)d_out;
  float* partial = (float*)d_ws;

  dim3 grid(IMG_W / TILE_W, IMG_H / TILE_H, NPLANES);  // 8 x 32 x 48 = 12288
  dim3 block(256, 1, 1);
  ssim_tile_kernel<<<grid, block, 0, stream>>>(enhanced, target, partial);

  const int nblocks = (IMG_W / TILE_W) * (IMG_H / TILE_H) * NPLANES;
  ssim_reduce_kernel<<<1, 1024, 0, stream>>>(partial, nblocks, out);
}